// Round 3
// baseline (45.332 us; speedup 1.0000x reference)
//
#include <hip/hip_runtime.h>

#define NB 128
#define NQ 1000
#define NG 300
#define NK 4
#define THRESH 0.4f

#define QCHUNKS 4                  // 256 queries per block
#define GCHUNKS 2                  // 150 GTs per block
#define GPERB   (NG / GCHUNKS)     // 150
#define QCAP    16                 // per-lane LDS queue capacity
#define CAPG    32                 // per-(b,g) global candidate slot capacity

// ws layout: [0, NB*NG*4) u32 counters ; then NB*NG*CAPG u16 slots.
#define CNT_BYTES ((size_t)NB * NG * 4)

// ---------------------------------------------------------------------------
// Kernel 1: exact-threshold prefilter. thread <-> query (pred box in regs),
// loop over GTs (box broadcast from LDS). iou>0.4 <=> 3.5*inter > pa+ta, so
// test fma(inter,3.5,-0.999pa) >= 0.999ta : 0.1% conservative margin >> f32
// rounding => no true positive is ever dropped; the few false positives
// (iou in [0.3997,0.4]) are removed by kernel 2's exact math.
// ---------------------------------------------------------------------------
__global__ __launch_bounds__(256) void filter_kernel(
    const float* __restrict__ pboxes,      // [B,Q,4]
    const float* __restrict__ tboxes,      // [B,G,4]
    unsigned int* __restrict__ cnts,       // [B,G]
    unsigned short* __restrict__ slots)    // [B,G,CAPG]
{
    __shared__ float4 stb[GPERB + 1];
    __shared__ float  sta[GPERB + 1];
    __shared__ unsigned short queue[QCAP * 256];  // [slot][tid] layout

    const int b   = blockIdx.y;
    const int qc  = blockIdx.x & (QCHUNKS - 1);
    const int gc  = blockIdx.x >> 2;
    const int tid = threadIdx.x;
    const int q   = qc * 256 + tid;
    const int g0  = gc * GPERB;

    // Stage this g-chunk's target boxes + pre-scaled areas into LDS.
    const float4* tb4 =
        reinterpret_cast<const float4*>(tboxes) + (size_t)b * NG + g0;
    for (int i = tid; i < GPERB; i += 256) {
        float4 t = tb4[i];
        stb[i] = t;
        sta[i] = 0.999f * ((t.z - t.x) * (t.w - t.y));
    }
    if (tid == 0) {
        stb[GPERB] = make_float4(0.f, 0.f, 0.f, 0.f);
        sta[GPERB] = 0.f;
    }

    // This thread's pred box (registers for the whole GT loop).
    float4 p;
    if (q < NQ) {
        p = reinterpret_cast<const float4*>(pboxes)[(size_t)b * NQ + q];
    } else {
        p = make_float4(2e9f, 2e9f, 2e9f, 2e9f);  // degenerate: never passes
    }
    const float pa999 = 0.999f * ((p.z - p.x) * (p.w - p.y));

    __syncthreads();

    int cnt = 0;
    float4 tb = stb[0];
    float  ta = sta[0];
    for (int gi = 0; gi < GPERB; ++gi) {
        float4 tbn  = stb[gi + 1];   // prefetch next (uniform broadcast)
        float  tan_ = sta[gi + 1];

        float ltx = fmaxf(p.x, tb.x);
        float lty = fmaxf(p.y, tb.y);
        float rbx = fminf(p.z, tb.z);
        float rby = fminf(p.w, tb.w);
        float w = fmaxf(rbx - ltx, 0.0f);
        float h = fmaxf(rby - lty, 0.0f);
        float inter = w * h;

        bool pass = fmaf(inter, 3.5f, -pa999) >= ta;
        if (pass && cnt < QCAP) {
            queue[cnt * 256 + tid] = (unsigned short)gi;
        }
        cnt += pass ? 1 : 0;

        tb = tbn;
        ta = tan_;
    }

    // Drain the (tiny) per-lane queue to global per-(b,g) candidate lists.
    int m = cnt < QCAP ? cnt : QCAP;
    unsigned int* cbase = cnts + (size_t)b * NG + g0;
    for (int i = 0; i < m; ++i) {
        int gi = queue[i * 256 + tid];
        unsigned pos = atomicAdd(cbase + gi, 1u);
        if (pos < CAPG) {
            slots[((size_t)b * NG + g0 + gi) * CAPG + pos] = (unsigned short)q;
        }
    }
}

// ---------------------------------------------------------------------------
// Kernel 2: one thread per (b,g). Exact reference math (round-1-verified op
// order: full IEEE div, same epsilon) on the <=32 candidates, top-4 via u64
// keys (valbits<<32)|~q = (value desc, index asc) exactly like jax.lax.top_k,
// zero-filler indices = smallest query indices not in the positive set.
// ---------------------------------------------------------------------------
__global__ __launch_bounds__(256) void select_kernel(
    const float* __restrict__ logits,      // [B,Q,1]
    const float* __restrict__ pboxes,      // [B,Q,4]
    const float* __restrict__ tboxes,      // [B,G,4]
    const unsigned int* __restrict__ cnts,
    const unsigned short* __restrict__ slots,
    float* __restrict__ out_vals,
    float* __restrict__ out_idx,
    float* __restrict__ out_mask)
{
    const int idx = blockIdx.x * 256 + threadIdx.x;
    if (idx >= NB * NG) return;
    const int b = idx / NG;

    const float4 tb = reinterpret_cast<const float4*>(tboxes)[idx];
    const float tarea = (tb.z - tb.x) * (tb.w - tb.y);

    int n = (int)cnts[idx];
    if (n > CAPG) n = CAPG;
    const unsigned short* sl = slots + (size_t)idx * CAPG;

    unsigned long long k0 = 0ull, k1 = 0ull, k2 = 0ull, k3 = 0ull;
    for (int i = 0; i < n; ++i) {
        const int q = sl[i];
        const float4 p =
            reinterpret_cast<const float4*>(pboxes)[(size_t)b * NQ + q];
        float parea = (p.z - p.x) * (p.w - p.y);
        float ltx = fmaxf(p.x, tb.x);
        float lty = fmaxf(p.y, tb.y);
        float rbx = fminf(p.z, tb.z);
        float rby = fminf(p.w, tb.w);
        float w = fmaxf(rbx - ltx, 0.0f);
        float h = fmaxf(rby - lty, 0.0f);
        float inter = w * h;
        float uni   = parea + tarea - inter;
        float iou   = inter / (uni + 1e-7f);
        if (iou > THRESH) {
            float x   = logits[(size_t)b * NQ + q];
            float sc  = 1.0f / (1.0f + expf(-x));
            float val = sc * iou;
            unsigned long long ck =
                ((unsigned long long)__float_as_uint(val) << 32) |
                (unsigned long long)(unsigned)(~(unsigned)q);
            if (ck > k3) {
                if (ck > k0)      { k3 = k2; k2 = k1; k1 = k0; k0 = ck; }
                else if (ck > k1) { k3 = k2; k2 = k1; k1 = ck; }
                else if (ck > k2) { k3 = k2; k2 = ck; }
                else              { k3 = ck; }
            }
        }
    }

    // Emit. Positives occupy the sorted prefix; fillers take the smallest
    // query indices not among the (<4) positives.
    const int iq0 = k0 ? (int)~(unsigned)k0 : -1;
    const int iq1 = k1 ? (int)~(unsigned)k1 : -1;
    const int iq2 = k2 ? (int)~(unsigned)k2 : -1;
    const size_t o = (size_t)idx * NK;
    int fill = 0;
#define EMIT(J, KJ)                                                         \
    {                                                                       \
        if (KJ != 0ull) {                                                   \
            out_vals[o + J] = __uint_as_float((unsigned)(KJ >> 32));        \
            out_idx[o + J]  = (float)(int)~(unsigned)KJ;                    \
            out_mask[o + J] = 1.0f;                                         \
        } else {                                                            \
            while (fill == iq0 || fill == iq1 || fill == iq2) ++fill;       \
            out_vals[o + J] = 0.0f;                                         \
            out_idx[o + J]  = (float)fill;                                  \
            out_mask[o + J] = 0.0f;                                         \
            ++fill;                                                         \
        }                                                                   \
    }
    EMIT(0, k0) EMIT(1, k1) EMIT(2, k2) EMIT(3, k3)
#undef EMIT
}

extern "C" void kernel_launch(void* const* d_in, const int* in_sizes, int n_in,
                              void* d_out, int out_size, void* d_ws, size_t ws_size,
                              hipStream_t stream) {
    const float* logits = (const float*)d_in[0];  // [128,1000,1]
    const float* pboxes = (const float*)d_in[1];  // [128,1000,4]
    const float* tboxes = (const float*)d_in[2];  // [128,300,4]

    float* out = (float*)d_out;
    const size_t bgk = (size_t)NB * NG * NK;      // 153600
    float* out_vals = out;
    float* out_idx  = out + bgk;
    float* out_mask = out + 2 * bgk;

    unsigned int*   cnts  = (unsigned int*)d_ws;
    unsigned short* slots = (unsigned short*)((char*)d_ws + CNT_BYTES);

    hipMemsetAsync(d_ws, 0, CNT_BYTES, stream);

    dim3 g1(QCHUNKS * GCHUNKS, NB);               // (8,128) = 1024 blocks
    filter_kernel<<<g1, 256, 0, stream>>>(pboxes, tboxes, cnts, slots);

    select_kernel<<<(NB * NG + 255) / 256, 256, 0, stream>>>(
        logits, pboxes, tboxes, cnts, slots, out_vals, out_idx, out_mask);
}

// Round 4
// 43.313 us; speedup vs baseline: 1.0466x; 1.0466x over previous
//
#include <hip/hip_runtime.h>

#define NB 128
#define NQ 1000
#define NG 300
#define NK 4
#define THRESH 0.4f

#define QCHUNKS 4                  // 256 queries per block
#define GCHUNKS 4                  // 75 GTs per block
#define GPERB   (NG / GCHUNKS)     // 75
#define QCAP    16                 // per-lane LDS queue capacity
#define CAPG    32                 // per-(b,g) global candidate slot capacity

// ws layout: [0, NB*NG*4) u32 counters ; then NB*NG*CAPG u16 slots.
#define CNT_BYTES ((size_t)NB * NG * 4)
#define NCNT      (NB * NG)        // 38400 u32

// ---------------------------------------------------------------------------
// Kernel 0: zero the counters. hipMemsetAsync's fillBufferAligned costs
// ~40 us per replay inside the graph (measured round 3); this is ~2 us.
// ---------------------------------------------------------------------------
__global__ __launch_bounds__(256) void zero_cnts(uint4* __restrict__ p)
{
    const int i = blockIdx.x * 256 + threadIdx.x;
    if (i < NCNT / 4) p[i] = make_uint4(0u, 0u, 0u, 0u);
}

// ---------------------------------------------------------------------------
// Kernel 1: exact-threshold prefilter. thread <-> query (pred box in regs),
// loop over GTs (box broadcast from LDS). iou>0.4 <=> 3.5*inter > pa+ta, so
// test fma(inter,3.5,-0.999pa) >= 0.999ta : 0.1% conservative margin >> f32
// rounding => no true positive is ever dropped; the few false positives
// (iou in [0.3997,0.4]) are removed by kernel 2's exact math.
// ---------------------------------------------------------------------------
__global__ __launch_bounds__(256) void filter_kernel(
    const float* __restrict__ pboxes,      // [B,Q,4]
    const float* __restrict__ tboxes,      // [B,G,4]
    unsigned int* __restrict__ cnts,       // [B,G]
    unsigned short* __restrict__ slots)    // [B,G,CAPG]
{
    __shared__ float4 stb[GPERB + 1];
    __shared__ float  sta[GPERB + 1];
    __shared__ unsigned short queue[QCAP * 256];  // [slot][tid] layout

    const int b   = blockIdx.y;
    const int qc  = blockIdx.x & (QCHUNKS - 1);
    const int gc  = blockIdx.x >> 2;
    const int tid = threadIdx.x;
    const int q   = qc * 256 + tid;
    const int g0  = gc * GPERB;

    // Stage this g-chunk's target boxes + pre-scaled areas into LDS.
    const float4* tb4 =
        reinterpret_cast<const float4*>(tboxes) + (size_t)b * NG + g0;
    if (tid < GPERB) {
        float4 t = tb4[tid];
        stb[tid] = t;
        sta[tid] = 0.999f * ((t.z - t.x) * (t.w - t.y));
    }
    if (tid == 0) {
        stb[GPERB] = make_float4(0.f, 0.f, 0.f, 0.f);
        sta[GPERB] = 0.f;
    }

    // This thread's pred box (registers for the whole GT loop).
    float4 p;
    if (q < NQ) {
        p = reinterpret_cast<const float4*>(pboxes)[(size_t)b * NQ + q];
    } else {
        p = make_float4(2e9f, 2e9f, 2e9f, 2e9f);  // degenerate: never passes
    }
    const float pa999 = 0.999f * ((p.z - p.x) * (p.w - p.y));

    __syncthreads();

    int cnt = 0;
    float4 tb = stb[0];
    float  ta = sta[0];
    for (int gi = 0; gi < GPERB; ++gi) {
        float4 tbn  = stb[gi + 1];   // prefetch next (uniform broadcast)
        float  tan_ = sta[gi + 1];

        float ltx = fmaxf(p.x, tb.x);
        float lty = fmaxf(p.y, tb.y);
        float rbx = fminf(p.z, tb.z);
        float rby = fminf(p.w, tb.w);
        float w = fmaxf(rbx - ltx, 0.0f);
        float h = fmaxf(rby - lty, 0.0f);
        float inter = w * h;

        bool pass = fmaf(inter, 3.5f, -pa999) >= ta;
        if (pass && cnt < QCAP) {
            queue[cnt * 256 + tid] = (unsigned short)gi;
        }
        cnt += pass ? 1 : 0;

        tb = tbn;
        ta = tan_;
    }

    // Drain the (tiny) per-lane queue to global per-(b,g) candidate lists.
    int m = cnt < QCAP ? cnt : QCAP;
    unsigned int* cbase = cnts + (size_t)b * NG + g0;
    for (int i = 0; i < m; ++i) {
        int gi = queue[i * 256 + tid];
        unsigned pos = atomicAdd(cbase + gi, 1u);
        if (pos < CAPG) {
            slots[((size_t)b * NG + g0 + gi) * CAPG + pos] = (unsigned short)q;
        }
    }
}

// ---------------------------------------------------------------------------
// Kernel 2: one thread per (b,g). Exact reference math (round-1-verified op
// order: full IEEE div, same epsilon) on the <=32 candidates, top-4 via u64
// keys (valbits<<32)|~q = (value desc, index asc) exactly like jax.lax.top_k,
// zero-filler indices = smallest query indices not in the positive set.
// ---------------------------------------------------------------------------
__global__ __launch_bounds__(256) void select_kernel(
    const float* __restrict__ logits,      // [B,Q,1]
    const float* __restrict__ pboxes,      // [B,Q,4]
    const float* __restrict__ tboxes,      // [B,G,4]
    const unsigned int* __restrict__ cnts,
    const unsigned short* __restrict__ slots,
    float* __restrict__ out_vals,
    float* __restrict__ out_idx,
    float* __restrict__ out_mask)
{
    const int idx = blockIdx.x * 256 + threadIdx.x;
    if (idx >= NB * NG) return;
    const int b = idx / NG;

    const float4 tb = reinterpret_cast<const float4*>(tboxes)[idx];
    const float tarea = (tb.z - tb.x) * (tb.w - tb.y);

    int n = (int)cnts[idx];
    if (n > CAPG) n = CAPG;
    const unsigned short* sl = slots + (size_t)idx * CAPG;

    unsigned long long k0 = 0ull, k1 = 0ull, k2 = 0ull, k3 = 0ull;
    for (int i = 0; i < n; ++i) {
        const int q = sl[i];
        const float4 p =
            reinterpret_cast<const float4*>(pboxes)[(size_t)b * NQ + q];
        float parea = (p.z - p.x) * (p.w - p.y);
        float ltx = fmaxf(p.x, tb.x);
        float lty = fmaxf(p.y, tb.y);
        float rbx = fminf(p.z, tb.z);
        float rby = fminf(p.w, tb.w);
        float w = fmaxf(rbx - ltx, 0.0f);
        float h = fmaxf(rby - lty, 0.0f);
        float inter = w * h;
        float uni   = parea + tarea - inter;
        float iou   = inter / (uni + 1e-7f);
        if (iou > THRESH) {
            float x   = logits[(size_t)b * NQ + q];
            float sc  = 1.0f / (1.0f + expf(-x));
            float val = sc * iou;
            unsigned long long ck =
                ((unsigned long long)__float_as_uint(val) << 32) |
                (unsigned long long)(unsigned)(~(unsigned)q);
            if (ck > k3) {
                if (ck > k0)      { k3 = k2; k2 = k1; k1 = k0; k0 = ck; }
                else if (ck > k1) { k3 = k2; k2 = k1; k1 = ck; }
                else if (ck > k2) { k3 = k2; k2 = ck; }
                else              { k3 = ck; }
            }
        }
    }

    // Emit. Positives occupy the sorted prefix; fillers take the smallest
    // query indices not among the (<4) positives.
    const int iq0 = k0 ? (int)~(unsigned)k0 : -1;
    const int iq1 = k1 ? (int)~(unsigned)k1 : -1;
    const int iq2 = k2 ? (int)~(unsigned)k2 : -1;
    const size_t o = (size_t)idx * NK;
    int fill = 0;
#define EMIT(J, KJ)                                                         \
    {                                                                       \
        if (KJ != 0ull) {                                                   \
            out_vals[o + J] = __uint_as_float((unsigned)(KJ >> 32));        \
            out_idx[o + J]  = (float)(int)~(unsigned)KJ;                    \
            out_mask[o + J] = 1.0f;                                         \
        } else {                                                            \
            while (fill == iq0 || fill == iq1 || fill == iq2) ++fill;       \
            out_vals[o + J] = 0.0f;                                         \
            out_idx[o + J]  = (float)fill;                                  \
            out_mask[o + J] = 0.0f;                                         \
            ++fill;                                                         \
        }                                                                   \
    }
    EMIT(0, k0) EMIT(1, k1) EMIT(2, k2) EMIT(3, k3)
#undef EMIT
}

extern "C" void kernel_launch(void* const* d_in, const int* in_sizes, int n_in,
                              void* d_out, int out_size, void* d_ws, size_t ws_size,
                              hipStream_t stream) {
    const float* logits = (const float*)d_in[0];  // [128,1000,1]
    const float* pboxes = (const float*)d_in[1];  // [128,1000,4]
    const float* tboxes = (const float*)d_in[2];  // [128,300,4]

    float* out = (float*)d_out;
    const size_t bgk = (size_t)NB * NG * NK;      // 153600
    float* out_vals = out;
    float* out_idx  = out + bgk;
    float* out_mask = out + 2 * bgk;

    unsigned int*   cnts  = (unsigned int*)d_ws;
    unsigned short* slots = (unsigned short*)((char*)d_ws + CNT_BYTES);

    zero_cnts<<<(NCNT / 4 + 255) / 256, 256, 0, stream>>>((uint4*)d_ws);

    dim3 g1(QCHUNKS * GCHUNKS, NB);               // (16,128) = 2048 blocks
    filter_kernel<<<g1, 256, 0, stream>>>(pboxes, tboxes, cnts, slots);

    select_kernel<<<(NB * NG + 255) / 256, 256, 0, stream>>>(
        logits, pboxes, tboxes, cnts, slots, out_vals, out_idx, out_mask);
}

// Round 5
// 28.153 us; speedup vs baseline: 1.6102x; 1.5385x over previous
//
#include <hip/hip_runtime.h>

#define NB 128
#define NQ 1000
#define NG 300
#define NK 4
#define THRESH 0.4f

#define GCHUNKS 4                  // GTs split across 4 blocks per batch
#define GPERB   (NG / GCHUNKS)     // 75 GTs per block
#define CAP     40                 // per-GT LDS candidate capacity

// ---------------------------------------------------------------------------
// Single fused kernel, NO workspace (the harness re-poisons d_ws with a
// 268 MB 0xAA fill inside the timed window -- measured ~39 us/replay in
// rounds 3/4 -- so any d_ws use costs more than the entire compute).
//
// Block = (batch b, GT-chunk gc). 1024 threads <-> queries. Phase 1: exact
// conservative prefilter (iou>0.4 <=> 3.5*inter > pa+ta; 0.1% margin => no
// true positive dropped; rare false positives removed by phase 2's exact
// math). Passing queries pushed to per-GT LDS lists via LDS atomics.
// Phase 2: thread <-> GT, exact reference-identical math (full IEEE div,
// same epsilon/op order), top-4 via u64 keys (valbits<<32)|~q which orders
// (value desc, index asc) exactly like jax.lax.top_k; zero-filler indices =
// smallest query indices not in the positive set. Validated absmax=0.0 in
// rounds 3/4.
// ---------------------------------------------------------------------------
__global__ __launch_bounds__(1024) void fused_matcher(
    const float* __restrict__ logits,      // [B,Q,1]
    const float* __restrict__ pboxes,      // [B,Q,4]
    const float* __restrict__ tboxes,      // [B,G,4]
    float* __restrict__ out_vals,          // [B,G,K]
    float* __restrict__ out_idx,           // [B,G,K] (as float)
    float* __restrict__ out_mask)          // [B,G,K] (0/1 float)
{
    __shared__ float4 spb[1024];               // 16 KB pred boxes
    __shared__ float  sscore[1024];            //  4 KB sigmoid scores
    __shared__ float4 stb[GPERB];              // target boxes
    __shared__ float  sta[GPERB];              // 0.999 * target area
    __shared__ unsigned scnt[GPERB];           // per-GT candidate counts
    __shared__ unsigned short sslot[GPERB][CAP];  // 6 KB candidate q lists

    const int b   = blockIdx.y;
    const int gc  = blockIdx.x;
    const int tid = threadIdx.x;
    const int g0  = gc * GPERB;

    // ---- Stage: pred box + score per thread; GT boxes; zero counters. ----
    float4 p;
    float  s = 0.0f;
    if (tid < NQ) {
        p = reinterpret_cast<const float4*>(pboxes)[(size_t)b * NQ + tid];
        float x = logits[(size_t)b * NQ + tid];
        s = 1.0f / (1.0f + expf(-x));
    } else {
        p = make_float4(2e9f, 2e9f, 2e9f, 2e9f);  // inter=0, area=0: never passes
    }
    spb[tid]    = p;
    sscore[tid] = s;
    const float pa999 = 0.999f * ((p.z - p.x) * (p.w - p.y));

    if (tid < GPERB) {
        float4 t = reinterpret_cast<const float4*>(tboxes)[(size_t)b * NG + g0 + tid];
        stb[tid]  = t;
        sta[tid]  = 0.999f * ((t.z - t.x) * (t.w - t.y));
        scnt[tid] = 0u;
    }
    __syncthreads();

    // ---- Phase 1: prefilter (thread <-> query, GTs broadcast from LDS). ----
#pragma unroll 5
    for (int gi = 0; gi < GPERB; ++gi) {
        const float4 tb = stb[gi];   // wave-uniform broadcast read
        const float  ta = sta[gi];

        float ltx = fmaxf(p.x, tb.x);
        float lty = fmaxf(p.y, tb.y);
        float rbx = fminf(p.z, tb.z);
        float rby = fminf(p.w, tb.w);
        float w = fmaxf(rbx - ltx, 0.0f);
        float h = fmaxf(rby - lty, 0.0f);
        float inter = w * h;

        if (fmaf(inter, 3.5f, -pa999) >= ta) {
            unsigned pos = atomicAdd(&scnt[gi], 1u);
            if (pos < CAP) sslot[gi][pos] = (unsigned short)tid;
        }
    }
    __syncthreads();

    // ---- Phase 2: exact select (thread <-> GT). ----
    if (tid < GPERB) {
        const float4 tb = stb[tid];
        const float tarea = (tb.z - tb.x) * (tb.w - tb.y);
        int n = (int)scnt[tid];
        if (n > CAP) n = CAP;

        unsigned long long k0 = 0ull, k1 = 0ull, k2 = 0ull, k3 = 0ull;
        for (int i = 0; i < n; ++i) {
            const int q = sslot[tid][i];
            const float4 pp = spb[q];
            float parea = (pp.z - pp.x) * (pp.w - pp.y);
            float ltx = fmaxf(pp.x, tb.x);
            float lty = fmaxf(pp.y, tb.y);
            float rbx = fminf(pp.z, tb.z);
            float rby = fminf(pp.w, tb.w);
            float w = fmaxf(rbx - ltx, 0.0f);
            float h = fmaxf(rby - lty, 0.0f);
            float inter = w * h;
            float uni   = parea + tarea - inter;
            float iou   = inter / (uni + 1e-7f);
            if (iou > THRESH) {
                float val = sscore[q] * iou;
                unsigned long long ck =
                    ((unsigned long long)__float_as_uint(val) << 32) |
                    (unsigned long long)(unsigned)(~(unsigned)q);
                if (ck > k3) {
                    if (ck > k0)      { k3 = k2; k2 = k1; k1 = k0; k0 = ck; }
                    else if (ck > k1) { k3 = k2; k2 = k1; k1 = ck; }
                    else if (ck > k2) { k3 = k2; k2 = ck; }
                    else              { k3 = ck; }
                }
            }
        }

        // Emit (float4 stores; K=4 slots are 16B-aligned).
        const int iq0 = k0 ? (int)~(unsigned)k0 : -1;
        const int iq1 = k1 ? (int)~(unsigned)k1 : -1;
        const int iq2 = k2 ? (int)~(unsigned)k2 : -1;
        float4 vv, vi, vm;
        float* pv = &vv.x; float* pi_ = &vi.x; float* pm = &vm.x;
        int fill = 0;
        unsigned long long ks[1];  // avoid runtime-indexed u64 array: unroll
#define EMIT(J, KJ)                                                         \
        {                                                                   \
            if (KJ != 0ull) {                                               \
                pv[J]  = __uint_as_float((unsigned)(KJ >> 32));             \
                pi_[J] = (float)(int)~(unsigned)KJ;                         \
                pm[J]  = 1.0f;                                              \
            } else {                                                        \
                while (fill == iq0 || fill == iq1 || fill == iq2) ++fill;   \
                pv[J]  = 0.0f;                                              \
                pi_[J] = (float)fill;                                       \
                pm[J]  = 0.0f;                                              \
                ++fill;                                                     \
            }                                                               \
        }
        EMIT(0, k0) EMIT(1, k1) EMIT(2, k2) EMIT(3, k3)
#undef EMIT
        (void)ks;
        const size_t o4 = (size_t)b * NG + g0 + tid;  // float4 index
        reinterpret_cast<float4*>(out_vals)[o4] = vv;
        reinterpret_cast<float4*>(out_idx)[o4]  = vi;
        reinterpret_cast<float4*>(out_mask)[o4] = vm;
    }
}

extern "C" void kernel_launch(void* const* d_in, const int* in_sizes, int n_in,
                              void* d_out, int out_size, void* d_ws, size_t ws_size,
                              hipStream_t stream) {
    const float* logits = (const float*)d_in[0];  // [128,1000,1]
    const float* pboxes = (const float*)d_in[1];  // [128,1000,4]
    const float* tboxes = (const float*)d_in[2];  // [128,300,4]

    float* out = (float*)d_out;
    const size_t bgk = (size_t)NB * NG * NK;      // 153600
    float* out_vals = out;
    float* out_idx  = out + bgk;
    float* out_mask = out + 2 * bgk;

    dim3 grid(GCHUNKS, NB);                       // (4,128) = 512 blocks
    fused_matcher<<<grid, 1024, 0, stream>>>(logits, pboxes, tboxes,
                                             out_vals, out_idx, out_mask);
}